// Round 9
// baseline (115.471 us; speedup 1.0000x reference)
//
#include <hip/hip_runtime.h>
#include <math.h>

#define B 8
#define NPTS 4096
#define QPT 8           // queries per thread in chamfer
#define THREADS 256

typedef float v2f __attribute__((ext_vector_type(2)));
typedef float v4f __attribute__((ext_vector_type(4)));

// ws layout: [partial: 2*B*S*NPTS f][sums32: 32 f][h1p: 64*256 f][nlls: 8 f]
// partial[((dir*B+b)*S + split)*NPTS + q]
// sums32 zeroed in D1, atomicAdd'ed by D2, plain-read by D3 (dispatch
// boundaries publish; no fences — R5 lesson; no serial atomic-read chains —
// R7 lesson; QPT capped so VGPR < 128 — R8 lesson).

// ======== D1: 32*S chamfer + 64 MLP-L1 + 1 init block ===================
// dist(q,t) = |q|^2 + 2*s,  s = |t|^2/2 - q.t   (packed: 2 refs per v2f lane)
template<int S, int LOG2S>
__global__ __launch_bounds__(THREADS, 4) void k_main(
    const float* __restrict__ pred, const float* __restrict__ targ,
    const float* __restrict__ x, const float* __restrict__ W1,
    float* __restrict__ partial, float* __restrict__ sums32,
    float* __restrict__ h1p) {
  constexpr int REFS = NPTS / S;      // 64 for S=64
  constexpr int PAIRS = REFS / 2;     // 32
  int id = blockIdx.x, tid = threadIdx.x;
  __shared__ v4f refsP[REFS < 64 ? 64 : REFS];   // [2p]=(x0,x1,y0,y1) [2p+1]=(z0,z1,w0,w1)

  if (id >= 32 * S) {
    if (id == 32 * S + 64) {            // init block: zero sums32
      if (tid < 32) sums32[tid] = 0.f;
      return;
    }
    // ---- MLP layer-1 partials: h1p[(b*8+kc)*256+j] = sum_k x[b,k]W1[k,j]
    int lid = id - 32 * S;
    int b = lid >> 3, kc = lid & 7;
    float* xs = (float*)refsP;
    if (tid < 64) xs[tid] = x[b * 512 + kc * 64 + tid];
    __syncthreads();
    float acc = 0.f;
    const float* w = W1 + (size_t)(kc * 64) * 256 + tid;
#pragma unroll 8
    for (int k = 0; k < 64; ++k) acc = fmaf(xs[k], w[k * 256], acc);
    h1p[(b * 8 + kc) * 256 + tid] = acc;
    return;
  }

  // ---------------- chamfer split-partial mins ----------------
  int split  = id & (S - 1);
  int qchunk = (id >> LOG2S) & 1;
  int b      = (id >> (LOG2S + 1)) & 7;
  int dir    = id >> (LOG2S + 4);
  const float* qp = dir ? targ : pred;
  const float* rp = dir ? pred : targ;

  const float* rb = rp + ((size_t)b * NPTS + (size_t)split * REFS) * 3;
  for (int p = tid; p < PAIRS; p += THREADS) {
    const float* r0 = rb + 6 * p;
    float x0 = r0[0], y0 = r0[1], z0 = r0[2];
    float x1 = r0[3], y1 = r0[4], z1 = r0[5];
    v4f A, Bv;
    A.x = x0; A.y = x1; A.z = y0; A.w = y1;
    Bv.x = z0; Bv.y = z1;
    Bv.z = 0.5f * fmaf(x0, x0, fmaf(y0, y0, z0 * z0));
    Bv.w = 0.5f * fmaf(x1, x1, fmaf(y1, y1, z1 * z1));
    refsP[2 * p]     = A;
    refsP[2 * p + 1] = Bv;
  }
  __syncthreads();

  const float* qb = qp + (size_t)b * NPTS * 3;
  int q0 = qchunk * (QPT * THREADS) + tid;
  v2f qx[QPT], qy[QPT], qz[QPT];      // negated splats
  float vmin[QPT];
#pragma unroll
  for (int i = 0; i < QPT; ++i) {
    int q = q0 + i * THREADS;
    float xx = qb[q * 3 + 0], yy = qb[q * 3 + 1], zz = qb[q * 3 + 2];
    qx[i].x = -xx; qx[i].y = -xx;
    qy[i].x = -yy; qy[i].y = -yy;
    qz[i].x = -zz; qz[i].y = -zz;
    vmin[i] = 3.4e38f;
  }

  for (int p = 0; p < PAIRS; p += 4) {
    v4f a0 = refsP[2 * p + 0], b0 = refsP[2 * p + 1];
    v4f a1 = refsP[2 * p + 2], b1 = refsP[2 * p + 3];
    v4f a2 = refsP[2 * p + 4], b2 = refsP[2 * p + 5];
    v4f a3 = refsP[2 * p + 6], b3 = refsP[2 * p + 7];
    // anti-remat pins (one operand per b128 tuple)
    asm volatile("" : "+v"(a0), "+v"(b0), "+v"(a1), "+v"(b1),
                      "+v"(a2), "+v"(b2), "+v"(a3), "+v"(b3));
#pragma unroll
    for (int i = 0; i < QPT; ++i) {
      v2f s0 = __builtin_elementwise_fma(qz[i], b0.xy, (v2f)b0.zw);
      s0 = __builtin_elementwise_fma(qy[i], a0.zw, s0);
      s0 = __builtin_elementwise_fma(qx[i], a0.xy, s0);
      v2f s1 = __builtin_elementwise_fma(qz[i], b1.xy, (v2f)b1.zw);
      s1 = __builtin_elementwise_fma(qy[i], a1.zw, s1);
      s1 = __builtin_elementwise_fma(qx[i], a1.xy, s1);
      v2f s2 = __builtin_elementwise_fma(qz[i], b2.xy, (v2f)b2.zw);
      s2 = __builtin_elementwise_fma(qy[i], a2.zw, s2);
      s2 = __builtin_elementwise_fma(qx[i], a2.xy, s2);
      v2f s3 = __builtin_elementwise_fma(qz[i], b3.xy, (v2f)b3.zw);
      s3 = __builtin_elementwise_fma(qy[i], a3.zw, s3);
      s3 = __builtin_elementwise_fma(qx[i], a3.xy, s3);
      float m0 = fminf(fminf(s0.x, s0.y), fminf(s1.x, s1.y));
      float m1 = fminf(fminf(s2.x, s2.y), fminf(s3.x, s3.y));
      vmin[i] = fminf(vmin[i], fminf(m0, m1));
    }
  }

  size_t base = (((size_t)dir * B + b) * S + split) * NPTS;
#pragma unroll
  for (int i = 0; i < QPT; ++i) {
    float xx = qx[i].x, yy = qy[i].x, zz = qz[i].x;   // negation squares away
    float qn = fmaf(xx, xx, fmaf(yy, yy, zz * zz));
    partial[base + q0 + i * THREADS] = fmaf(2.f, vmin[i], qn);
  }
}

// ======== D2: 64 vec-reduce blocks + 1 MLP(L2/L3/NLL) block =============
template<int S>
__global__ __launch_bounds__(THREADS) void k_finish(
    const float* __restrict__ partial, float* __restrict__ sums32,
    const float* __restrict__ h1p, const float* __restrict__ b1,
    const float* __restrict__ W2, const float* __restrict__ b2,
    const float* __restrict__ W3, const float* __restrict__ b3,
    const int* __restrict__ labels, float* __restrict__ nlls) {
  int id = blockIdx.x, tid = threadIdx.x;
  __shared__ float sbuf[4160];     // 16.6 KB arena

  if (id < 64) {
    // q-major vectorized reduce: thread owns 4 consecutive q's; S independent
    // float4 loads pipeline on vmcnt (R6 lesson: scalar strided was 30x off).
    int dirb  = id >> 2;                 // dir*8+b
    int chunk = id & 3;
    const float* pbase = partial + (size_t)dirb * S * NPTS
                       + (size_t)chunk * 1024 + (size_t)tid * 4;
    float4 m4 = make_float4(3.4e38f, 3.4e38f, 3.4e38f, 3.4e38f);
#pragma unroll 8
    for (int s = 0; s < S; ++s) {
      float4 v = *(const float4*)(pbase + (size_t)s * NPTS);
      m4.x = fminf(m4.x, v.x); m4.y = fminf(m4.y, v.y);
      m4.z = fminf(m4.z, v.z); m4.w = fminf(m4.w, v.w);
    }
    float s_min  = (m4.x + m4.y) + (m4.z + m4.w);
    float s_soft = (__expf(-5000.0f * m4.x) + __expf(-5000.0f * m4.y))
                 + (__expf(-5000.0f * m4.z) + __expf(-5000.0f * m4.w));
    for (int off = 32; off > 0; off >>= 1) {
      s_min  += __shfl_down(s_min,  off);
      s_soft += __shfl_down(s_soft, off);
    }
    int wave = tid >> 6, lane = tid & 63;
    if (lane == 0) { sbuf[wave * 2] = s_min; sbuf[wave * 2 + 1] = s_soft; }
    __syncthreads();
    if (tid == 0) {
      float a = 0.f, c = 0.f;
      for (int w = 0; w < 4; ++w) { a += sbuf[w * 2]; c += sbuf[w * 2 + 1]; }
      atomicAdd(&sums32[dirb * 2 + 0], a);
      atomicAdd(&sums32[dirb * 2 + 1], c);
    }
    return;
  }

  // ---- MLP block (id==64): L2 + L3 + NLL ----
  float* h1s = sbuf;            // 2048
  float* pp  = sbuf + 2048;     // 2048
  float* lg  = sbuf + 4096;     // 48
  for (int i = tid; i < 2048; i += THREADS) {
    int bb = i >> 8, j = i & 255;
    float a = b1[j];
#pragma unroll
    for (int kc = 0; kc < 8; ++kc) a += h1p[(bb * 8 + kc) * 256 + j];
    h1s[i] = fmaxf(a, 0.f);
  }
  __syncthreads();
  {
    int j = tid & 127, half = tid >> 7;
    float acc[8];
#pragma unroll
    for (int bb = 0; bb < 8; ++bb) acc[bb] = 0.f;
    const float* w = W2 + (size_t)(half * 128) * 128 + j;
    for (int k = 0; k < 128; ++k) {
      float wv = w[k * 128];
      int kk = half * 128 + k;
#pragma unroll
      for (int bb = 0; bb < 8; ++bb)
        acc[bb] = fmaf(h1s[bb * 256 + kk], wv, acc[bb]);
    }
#pragma unroll
    for (int bb = 0; bb < 8; ++bb) pp[(half * 8 + bb) * 128 + j] = acc[bb];
  }
  __syncthreads();
  float* h2s = sbuf;            // reuse (h1s dead)
  for (int i = tid; i < 1024; i += THREADS) {
    int bb = i >> 7, j = i & 127;
    float a = b2[j] + pp[(0 * 8 + bb) * 128 + j] + pp[(1 * 8 + bb) * 128 + j];
    h2s[i] = fmaxf(a, 0.f);
  }
  __syncthreads();
  if (tid < 48) {
    int bb = tid / 6, d = tid % 6;
    float acc = b3[d];
#pragma unroll 8
    for (int k = 0; k < 128; ++k) acc = fmaf(h2s[bb * 128 + k], W3[k * 6 + d], acc);
    lg[tid] = acc;
  }
  __syncthreads();
  if (tid < 8) {
    int bb = tid;
    float mx = lg[bb * 6];
    for (int d = 1; d < 6; ++d) mx = fmaxf(mx, lg[bb * 6 + d]);
    float se = 0.f;
    for (int d = 0; d < 6; ++d) se += __expf(lg[bb * 6 + d] - mx);
    int lab = labels[bb];
    nlls[bb] = -(lg[bb * 6 + lab] - mx - __logf(se));
  }
}

// ======== D3: final combine, 1 block, plain loads =======================
__global__ __launch_bounds__(64) void k_combine(
    const float* __restrict__ sums32, const float* __restrict__ nlls,
    const float* __restrict__ w, float* __restrict__ out) {
  if (threadIdx.x != 0) return;
  float chamfer = 0.f, prec = 0.f, rec = 0.f, dsw = 0.f, dom = 0.f;
  for (int b = 0; b < B; ++b) {
    float sa  = sums32[(0 * B + b) * 2 + 0];
    float ssa = sums32[(0 * B + b) * 2 + 1];
    float sb  = sums32[(1 * B + b) * 2 + 0];
    float ssb = sums32[(1 * B + b) * 2 + 1];
    float ma = sa / 4096.f, mb = sb / 4096.f;
    float p = ssa / 4096.f, r = ssb / 4096.f;
    chamfer += ma + mb;
    prec += p; rec += r;
    float f_i = 2.f * p * r / (p + r + 1e-8f);
    float loss_i = ma + mb + 0.1f * (1.f - f_i);
    dsw += w[b] * loss_i;
    dom += nlls[b];
  }
  chamfer *= (1.f / B); prec *= (1.f / B); rec *= (1.f / B);
  dsw *= (1.f / B); dom *= (1.f / B);
  float fscore = 2.f * prec * rec / (prec + rec + 1e-8f);
  float task = chamfer + 0.1f * (1.f - fscore);
  out[0] = 1.0f * task + 0.1f * dom + dsw;
}

template<int S, int LOG2S>
static void run_pipeline(const float* pred, const float* targ, const float* x,
                         const float* wgt, const float* W1, const float* b1,
                         const float* W2, const float* b2, const float* W3,
                         const float* b3, const int* labels, float* out,
                         char* ws, hipStream_t stream) {
  float* partial = (float*)ws;
  float* sums32  = partial + (size_t)2 * B * S * NPTS;
  float* h1p     = sums32 + 32;
  float* nlls    = h1p + 64 * 256;

  hipLaunchKernelGGL((k_main<S, LOG2S>), dim3(32 * S + 65), dim3(THREADS), 0,
                     stream, pred, targ, x, W1, partial, sums32, h1p);
  hipLaunchKernelGGL((k_finish<S>), dim3(65), dim3(THREADS), 0, stream,
                     partial, sums32, h1p, b1, W2, b2, W3, b3, labels, nlls);
  hipLaunchKernelGGL(k_combine, dim3(1), dim3(64), 0, stream,
                     sums32, nlls, wgt, out);
}

extern "C" void kernel_launch(void* const* d_in, const int* in_sizes, int n_in,
                              void* d_out, int out_size, void* d_ws, size_t ws_size,
                              hipStream_t stream) {
  const float* pred   = (const float*)d_in[0];
  const float* targ   = (const float*)d_in[1];
  const float* x      = (const float*)d_in[2];
  const float* wgt    = (const float*)d_in[3];
  const float* W1     = (const float*)d_in[4];
  const float* b1     = (const float*)d_in[5];
  const float* W2     = (const float*)d_in[6];
  const float* b2     = (const float*)d_in[7];
  const float* W3     = (const float*)d_in[8];
  const float* b3     = (const float*)d_in[9];
  const int*   labels = (const int*)d_in[10];
  float* out = (float*)d_out;
  char* ws = (char*)d_ws;

  auto need = [](int S) {
    return ((size_t)2 * B * S * NPTS + 32 + 64 * 256 + 8) * sizeof(float);
  };
  if (ws_size >= need(64))
    run_pipeline<64, 6>(pred, targ, x, wgt, W1, b1, W2, b2, W3, b3, labels,
                        out, ws, stream);
  else if (ws_size >= need(32))
    run_pipeline<32, 5>(pred, targ, x, wgt, W1, b1, W2, b2, W3, b3, labels,
                        out, ws, stream);
  else
    run_pipeline<16, 4>(pred, targ, x, wgt, W1, b1, W2, b2, W3, b3, labels,
                        out, ws, stream);
}